// Round 1
// 316.663 us; speedup vs baseline: 1.0906x; 1.0906x over previous
//
#include <hip/hip_runtime.h>
#include <stdint.h>

#define N_K   10000
#define CIN   3
#define SEQ   1000
#define KM    11
#define NCLS  4096   // class buckets: (d-1)*4 + padflag*2 + padsize-bit
#define NSP   2048   // span (out_len) sort buckets
#define MAXQ  5632   // upper bound on quad count
#define QPB   8      // quads per block
#define NB    4      // batches per block

typedef _Float16 h2 __attribute__((ext_vector_type(2)));

// ---------------- prep: group j by (d, pad-class), form quads, sort by span --
__global__ __launch_bounds__(1024) void prep_kernel(
    const int* __restrict__ dil, const int* __restrict__ start,
    const int* __restrict__ out_len, const int* __restrict__ pad_max_p,
    int* __restrict__ sortedj, int2* __restrict__ quads) {
  __shared__ int cA[NCLS];
  __shared__ int cB[NCLS];
  __shared__ int cC[NSP];
  __shared__ int sh_total;
  const int tid = threadIdx.x;
  const int pm = pad_max_p[0];
  for (int i = tid; i < NCLS; i += 1024) cA[i] = 0;
  if (tid == 0) sh_total = 0;
  __syncthreads();
  // class histogram: all members of a class share d (exact); pad bits only
  // tighten span homogeneity (correctness never depends on bucketing).
  for (int j = tid; j < N_K; j += 1024) {
    int d = dil[j];
    int pads = pm - start[j];
    int kk = (d - 1) * 4 + (pads > 0 ? 2 : 0) + (2 * pads > 7 * d ? 1 : 0);
    kk = min(kk, NCLS - 1);
    atomicAdd(&cA[kk], 1);
  }
  __syncthreads();
  {  // inclusive scan of cA; 12 rounds (even) -> result lands back in cA
    int* cur = cA; int* oth = cB;
    for (int off = 1; off < NCLS; off <<= 1) {
      for (int i = tid; i < NCLS; i += 1024) {
        int v = cur[i];
        if (i >= off) v += cur[i - off];
        oth[i] = v;
      }
      __syncthreads();
      int* t = cur; cur = oth; oth = t;
    }
  }
  for (int i = tid; i < NCLS; i += 1024) cB[i] = i ? cA[i - 1] : 0;  // exclusive
  __syncthreads();
  for (int j = tid; j < N_K; j += 1024) {
    int d = dil[j];
    int pads = pm - start[j];
    int kk = (d - 1) * 4 + (pads > 0 ? 2 : 0) + (2 * pads > 7 * d ? 1 : 0);
    kk = min(kk, NCLS - 1);
    int pos = atomicAdd(&cB[kk], 1);
    sortedj[pos] = j;
  }
  __syncthreads();
  for (int i = tid; i < NSP; i += 1024) cC[i] = 0;
  __syncthreads();
  // phase A: per class, count quads into span bucket (rep member's out_len)
  for (int c = tid; c < NCLS; c += 1024) {
    int incl = cA[c];
    int n = incl - (c ? cA[c - 1] : 0);
    if (n <= 0) continue;
    int st = incl - n;
    int nq = (n + 3) >> 2;
    int espan = out_len[sortedj[st]];
    int sb = (NSP - 1) - min(espan, NSP - 1);   // descending span order
    atomicAdd(&cC[sb], nq);
    atomicAdd(&sh_total, nq);
  }
  __syncthreads();
  {  // inclusive scan of cC; 11 rounds (odd) -> result lands in cB
    int* cur = cC; int* oth = cB;
    for (int off = 1; off < NSP; off <<= 1) {
      for (int i = tid; i < NSP; i += 1024) {
        int v = cur[i];
        if (i >= off) v += cur[i - off];
        oth[i] = v;
      }
      __syncthreads();
      int* t = cur; cur = oth; oth = t;
    }
  }
  for (int i = tid; i < NSP; i += 1024) cC[i] = i ? cB[i - 1] : 0;  // exclusive
  __syncthreads();
  // placement: quad record = (first member offset in sortedj, last valid offset)
  for (int c = tid; c < NCLS; c += 1024) {
    int incl = cA[c];
    int n = incl - (c ? cA[c - 1] : 0);
    if (n <= 0) continue;
    int st = incl - n;
    int nq = (n + 3) >> 2;
    int espan = out_len[sortedj[st]];
    int sb = (NSP - 1) - min(espan, NSP - 1);
    int pos = atomicAdd(&cC[sb], nq);
    for (int q = 0; q < nq; ++q)
      quads[pos + q] = make_int2(st + 4 * q, st + n - 1);
  }
  __syncthreads();
  int total = sh_total;
  for (int i = total + tid; i < MAXQ; i += 1024) quads[i] = make_int2(-1, -1);
}

// ---------------- main kernel ------------------------------------------------
// block 256 = 8 quads x 4 batches x 8 tau-slices.
// Each thread computes 4 same-d kernels per x-tap read (DS traffic / 4).
// __launch_bounds__(256, 4): cap 4 waves/EU -> 128 VGPR budget so the 68
// weight regs + 11 tap regs + p[] stay register-resident (at the default
// allocation of 80 VGPRs the weights cannot all be live -> hot-loop spills).
__global__ __launch_bounds__(256, 4) void rocket_kernel(
    const float* __restrict__ x, const float* __restrict__ w,
    const float* __restrict__ bias, const int* __restrict__ dil,
    const int* __restrict__ start, const int* __restrict__ out_len,
    const int* __restrict__ pad_max_p, const int* __restrict__ sortedj,
    const int2* __restrict__ quads, float* __restrict__ out) {
  __shared__ __align__(16) unsigned long long xs[NB * 1002];

  const int tid = threadIdx.x;
  const int h    = tid & 7;
  const int lb   = (tid >> 3) & 3;
  const int qloc = tid >> 5;
  const int bg = blockIdx.x & 3;
  const int qb = blockIdx.x >> 2;

  // Quads are placed in descending-span order and the tail is -1-filled, so
  // if this block's first quad is empty the whole block is: skip staging.
  if (quads[qb * QPB].x < 0) return;

  // stage x (4 batches) packed (c0,c1|c2,0) fp16 per position, zero sentinels
  for (int lbb = 0; lbb < NB; ++lbb) {
    const float* xb = x + (size_t)(bg * NB + lbb) * (CIN * SEQ);
    for (int pos = tid; pos < SEQ; pos += 256) {
      float a0 = xb[pos];
      float a1 = xb[SEQ + pos];
      float a2 = xb[2 * SEQ + pos];
      unsigned u0 = (unsigned)__builtin_bit_cast(unsigned short, (_Float16)a0);
      unsigned u1 = (unsigned)__builtin_bit_cast(unsigned short, (_Float16)a1);
      unsigned u2 = (unsigned)__builtin_bit_cast(unsigned short, (_Float16)a2);
      xs[lbb * 1002 + 1 + pos] =
          (unsigned long long)(u0 | (u1 << 16)) | ((unsigned long long)u2 << 32);
    }
  }
  if (tid < NB * 2) xs[(tid >> 1) * 1002 + (tid & 1) * 1001] = 0ULL;
  __syncthreads();

  int2 qr = quads[qb * QPB + qloc];
  if (qr.x < 0) return;

  int jm[4];
#pragma unroll
  for (int i = 0; i < 4; ++i) jm[i] = sortedj[min(qr.x + i, qr.y)];

  const int pm = pad_max_p[0];
  const int d = dil[jm[0]];  // class key guarantees same d for all members

  int sm[4], olm[4];
  float bb[4];
  int tlo = 0x7fffffff, thi = 0;
#pragma unroll
  for (int m = 0; m < 4; ++m) {
    sm[m] = start[jm[m]];
    olm[m] = out_len[jm[m]];
    bb[m] = bias[jm[m]];
    tlo = min(tlo, sm[m]);
    thi = max(thi, sm[m] + olm[m]);
  }

  // weight registers: (c0,c1) per member per tap; c2 packed per TAP-PAIR so
  // both fdot2 halves do useful work (f32 accumulation preserved);
  // tap 10 (odd one out) keeps the (c2,0) form.
  h2 wl[4][KM];    // (w_c0, w_c1) per member per tap
  h2 w2p[4][5];    // (w_c2[2p], w_c2[2p+1]) per member
  h2 w210[4];      // (w_c2[10], 0) per member
#pragma unroll
  for (int m = 0; m < 4; ++m) {
    const float* wj = w + (size_t)jm[m] * (CIN * KM);
#pragma unroll
    for (int k = 0; k < KM; ++k) {
      h2 a;
      a.x = (_Float16)wj[k];
      a.y = (_Float16)wj[KM + k];
      wl[m][k] = a;
    }
#pragma unroll
    for (int pp = 0; pp < 5; ++pp) {
      h2 a;
      a.x = (_Float16)wj[2 * KM + 2 * pp];
      a.y = (_Float16)wj[2 * KM + 2 * pp + 1];
      w2p[m][pp] = a;
    }
    {
      h2 a;
      a.x = (_Float16)wj[2 * KM + 10];
      a.y = (_Float16)0.0f;
      w210[m] = a;
    }
  }

  const int len = thi - tlo;
  const int ta = tlo + ((len * h) >> 3);
  const int tb = tlo + ((len * (h + 1)) >> 3);
  const int lbase = lb * 1002;
  const int clo = lbase, chi = lbase + 1001;

  int p[KM];
#pragma unroll
  for (int k = 0; k < KM; ++k) p[k] = lbase + 1 + (ta - pm) + k * d;

  float mx[4] = {-3.0e38f, -3.0e38f, -3.0e38f, -3.0e38f};
  int cnt[4] = {0, 0, 0, 0};

  for (int t = ta; t < tb; ++t) {
    unsigned long long v[KM];
#pragma unroll
    for (int k = 0; k < KM; ++k) {
      int q = min(max(p[k], clo), chi);    // v_med3, sentinels absorb OOB
      v[k] = xs[q];                         // ds_read_b64, shared by 4 j
      p[k]++;
    }
    float a0[4] = {bb[0], bb[1], bb[2], bb[3]};  // bias folded into init
    float a1[4] = {0.f, 0.f, 0.f, 0.f};
#pragma unroll
    for (int k = 0; k < KM; ++k) {
      h2 xl = __builtin_bit_cast(h2, (unsigned)v[k]);   // (c0, c1)
      a0[0] = __builtin_amdgcn_fdot2(xl, wl[0][k], a0[0], false);
      a0[1] = __builtin_amdgcn_fdot2(xl, wl[1][k], a0[1], false);
      a0[2] = __builtin_amdgcn_fdot2(xl, wl[2][k], a0[2], false);
      a0[3] = __builtin_amdgcn_fdot2(xl, wl[3][k], a0[3], false);
    }
#pragma unroll
    for (int pp = 0; pp < 5; ++pp) {
      unsigned hA = (unsigned)(v[2 * pp] >> 32);       // (c2@2p , 0)
      unsigned hB = (unsigned)(v[2 * pp + 1] >> 32);   // (c2@2p+1, 0)
      // (c2@2p, c2@2p+1) in one reg: one v_perm_b32
      h2 xp = __builtin_bit_cast(h2, __builtin_amdgcn_perm(hB, hA, 0x05040100u));
      a1[0] = __builtin_amdgcn_fdot2(xp, w2p[0][pp], a1[0], false);
      a1[1] = __builtin_amdgcn_fdot2(xp, w2p[1][pp], a1[1], false);
      a1[2] = __builtin_amdgcn_fdot2(xp, w2p[2][pp], a1[2], false);
      a1[3] = __builtin_amdgcn_fdot2(xp, w2p[3][pp], a1[3], false);
    }
    {
      h2 x10 = __builtin_bit_cast(h2, (unsigned)(v[10] >> 32));  // (c2, 0)
      a1[0] = __builtin_amdgcn_fdot2(x10, w210[0], a1[0], false);
      a1[1] = __builtin_amdgcn_fdot2(x10, w210[1], a1[1], false);
      a1[2] = __builtin_amdgcn_fdot2(x10, w210[2], a1[2], false);
      a1[3] = __builtin_amdgcn_fdot2(x10, w210[3], a1[3], false);
    }
#pragma unroll
    for (int m = 0; m < 4; ++m) {
      float val = a0[m] + a1[m];
      bool in = (unsigned)(t - sm[m]) < (unsigned)olm[m];
      float vm = in ? val : -3.0e38f;     // masked value, reused for count
      mx[m] = fmaxf(mx[m], vm);
      cnt[m] += (vm > 0.f) ? 1 : 0;       // mask already folded into vm
    }
  }

  // reduce across the 8 tau-slices (lanes differing in bits 0..2)
#pragma unroll
  for (int m = 0; m < 4; ++m) {
#pragma unroll
    for (int off = 1; off < 8; off <<= 1) {
      mx[m] = fmaxf(mx[m], __shfl_xor(mx[m], off));
      cnt[m] += __shfl_xor(cnt[m], off);
    }
  }

  if (h == 0) {
    const int b = bg * NB + lb;
#pragma unroll
    for (int m = 0; m < 4; ++m) {
      float2 r;
      r.x = mx[m];
      r.y = (float)cnt[m] / (float)olm[m];
      *(float2*)(out + (size_t)b * (2 * N_K) + 2 * jm[m]) = r;
    }
  }
}

extern "C" void kernel_launch(void* const* d_in, const int* in_sizes, int n_in,
                              void* d_out, int out_size, void* d_ws, size_t ws_size,
                              hipStream_t stream) {
  const float* x       = (const float*)d_in[0];
  const float* weight  = (const float*)d_in[1];
  const float* bias    = (const float*)d_in[2];
  const int*   dil     = (const int*)d_in[3];
  const int*   start   = (const int*)d_in[4];
  const int*   out_len = (const int*)d_in[5];
  const int*   pad_max = (const int*)d_in[6];
  (void)in_sizes; (void)n_in; (void)out_size; (void)ws_size;

  int2* quads   = (int2*)d_ws;                          // MAXQ int2
  int*  sortedj = (int*)((char*)d_ws + MAXQ * sizeof(int2));  // N_K ints

  prep_kernel<<<1, 1024, 0, stream>>>(dil, start, out_len, pad_max,
                                      sortedj, quads);

  rocket_kernel<<<(MAXQ / QPB) * 4, 256, 0, stream>>>(
      x, weight, bias, dil, start, out_len, pad_max, sortedj, quads,
      (float*)d_out);
}

// Round 2
// 315.114 us; speedup vs baseline: 1.0960x; 1.0049x over previous
//
#include <hip/hip_runtime.h>
#include <stdint.h>

#define N_K   10000
#define CIN   3
#define SEQ   1000
#define KM    11
#define NCLS  4096   // class key: ((d-1)*3 + ksidx)*4 + padflag*2 + padsize-bit
#define NSP   2048   // span (out_len) sort buckets per ks-region
#define QREG  2048   // quads per ks region (expected ~1350 max)
#define QPB   8      // quads per block
#define QBPR  (QREG / QPB)   // 256 quad-blocks per region
#define NB    4      // batches per block

typedef _Float16 h2 __attribute__((ext_vector_type(2)));

// ---------------- prep: group j by (d, ks, pad-class), form quads,
// ---------------- partition by ks into 3 regions, span-sort within region ----
__global__ __launch_bounds__(1024) void prep_kernel(
    const int* __restrict__ dil, const int* __restrict__ start,
    const int* __restrict__ out_len, const int* __restrict__ pad_max_p,
    int* __restrict__ sortedj, int2* __restrict__ quads) {
  __shared__ int cA[NCLS];
  __shared__ int cB[NCLS];
  __shared__ int cC[3 * NSP];
  __shared__ int cD[3 * NSP];
  __shared__ int sh_total[3];
  const int tid = threadIdx.x;
  const int pm = pad_max_p[0];
  for (int i = tid; i < NCLS; i += 1024) cA[i] = 0;
  if (tid < 3) sh_total[tid] = 0;
  __syncthreads();
  // class histogram. ks recovered exactly: out_len = SEQ + 2*pads - d*(ks-1).
  for (int j = tid; j < N_K; j += 1024) {
    int d = dil[j];
    int pads = pm - start[j];
    int ks = (SEQ + 2 * pads - out_len[j]) / d + 1;
    int kk = ((d - 1) * 3 + ((ks - 7) >> 1)) * 4 + (pads > 0 ? 2 : 0) +
             (2 * pads > 7 * d ? 1 : 0);
    kk = min(kk, NCLS - 1);
    atomicAdd(&cA[kk], 1);
  }
  __syncthreads();
  {  // inclusive scan of cA; 12 rounds (even) -> result lands back in cA
    int* cur = cA; int* oth = cB;
    for (int off = 1; off < NCLS; off <<= 1) {
      for (int i = tid; i < NCLS; i += 1024) {
        int v = cur[i];
        if (i >= off) v += cur[i - off];
        oth[i] = v;
      }
      __syncthreads();
      int* tp = cur; cur = oth; oth = tp;
    }
  }
  for (int i = tid; i < NCLS; i += 1024) cB[i] = i ? cA[i - 1] : 0;  // exclusive
  __syncthreads();
  for (int j = tid; j < N_K; j += 1024) {
    int d = dil[j];
    int pads = pm - start[j];
    int ks = (SEQ + 2 * pads - out_len[j]) / d + 1;
    int kk = ((d - 1) * 3 + ((ks - 7) >> 1)) * 4 + (pads > 0 ? 2 : 0) +
             (2 * pads > 7 * d ? 1 : 0);
    kk = min(kk, NCLS - 1);
    int pos = atomicAdd(&cB[kk], 1);
    sortedj[pos] = j;
  }
  __syncthreads();
  for (int i = tid; i < 3 * NSP; i += 1024) cC[i] = 0;
  __syncthreads();
  // per class: count quads into (ks-region, span) bucket
  for (int c = tid; c < NCLS; c += 1024) {
    int incl = cA[c];
    int n = incl - (c ? cA[c - 1] : 0);
    if (n <= 0) continue;
    int st = incl - n;
    int nq = (n + 3) >> 2;
    int ksidx = (c >> 2) % 3;
    int espan = out_len[sortedj[st]];
    int sb = ksidx * NSP + (NSP - 1) - min(espan, NSP - 1);  // descending span
    atomicAdd(&cC[sb], nq);
    atomicAdd(&sh_total[ksidx], nq);
  }
  __syncthreads();
  int* excl;
  {  // segmented (per-region) scan of cC; segments are NSP-aligned
    int* cur = cC; int* oth = cD;
    for (int off = 1; off < NSP; off <<= 1) {
      for (int i = tid; i < 3 * NSP; i += 1024) {
        int v = cur[i];
        if ((i & (NSP - 1)) >= off) v += cur[i - off];
        oth[i] = v;
      }
      __syncthreads();
      int* tp = cur; cur = oth; oth = tp;
    }
    for (int i = tid; i < 3 * NSP; i += 1024)
      oth[i] = (i & (NSP - 1)) ? cur[i - 1] : 0;  // per-segment exclusive
    __syncthreads();
    excl = oth;
  }
  // placement: quad = (first member offset in sortedj, last valid offset)
  for (int c = tid; c < NCLS; c += 1024) {
    int incl = cA[c];
    int n = incl - (c ? cA[c - 1] : 0);
    if (n <= 0) continue;
    int st = incl - n;
    int nq = (n + 3) >> 2;
    int ksidx = (c >> 2) % 3;
    int espan = out_len[sortedj[st]];
    int sb = ksidx * NSP + (NSP - 1) - min(espan, NSP - 1);
    int pos = atomicAdd(&excl[sb], nq);
    for (int qq = 0; qq < nq; ++qq)
      quads[ksidx * QREG + pos + qq] = make_int2(st + 4 * qq, st + n - 1);
  }
  __syncthreads();
  for (int s = 0; s < 3; ++s)
    for (int i = sh_total[s] + tid; i < QREG; i += 1024)
      quads[s * QREG + i] = make_int2(-1, -1);
}

// ---------------- main kernel body, specialized on KS -----------------------
// block 256 = 8 quads x 4 batches x 8 tau-slices (t interleaved mod 8 so the
// 8 slices read CONSECUTIVE LDS addresses -> no systematic bank conflicts).
// t-loop split head/interior/tail: interior needs no v_med3 clamp.
#define ROCKET_STEP(CLAMPED)                                               \
  do {                                                                     \
    unsigned long long v[KS];                                              \
    _Pragma("unroll") for (int k = 0; k < KS; ++k) {                       \
      int qq = p[k];                                                       \
      if (CLAMPED) qq = min(max(qq, clo), chi);                            \
      v[k] = xs[qq];                                                       \
      p[k] += 8;                                                           \
    }                                                                      \
    float a0[4] = {bb[0], bb[1], bb[2], bb[3]};                            \
    float a1[4] = {0.f, 0.f, 0.f, 0.f};                                    \
    _Pragma("unroll") for (int k = 0; k < KS; ++k) {                       \
      h2 xl = __builtin_bit_cast(h2, (unsigned)v[k]);                      \
      a0[0] = __builtin_amdgcn_fdot2(xl, wl[0][k], a0[0], false);          \
      a0[1] = __builtin_amdgcn_fdot2(xl, wl[1][k], a0[1], false);          \
      a0[2] = __builtin_amdgcn_fdot2(xl, wl[2][k], a0[2], false);          \
      a0[3] = __builtin_amdgcn_fdot2(xl, wl[3][k], a0[3], false);          \
    }                                                                      \
    _Pragma("unroll") for (int pp = 0; pp < NP; ++pp) {                    \
      unsigned hA = (unsigned)(v[2 * pp] >> 32);                           \
      unsigned hB = (unsigned)(v[2 * pp + 1] >> 32);                       \
      h2 xp = __builtin_bit_cast(                                          \
          h2, __builtin_amdgcn_perm(hB, hA, 0x05040100u));                 \
      a1[0] = __builtin_amdgcn_fdot2(xp, w2p[0][pp], a1[0], false);        \
      a1[1] = __builtin_amdgcn_fdot2(xp, w2p[1][pp], a1[1], false);        \
      a1[2] = __builtin_amdgcn_fdot2(xp, w2p[2][pp], a1[2], false);        \
      a1[3] = __builtin_amdgcn_fdot2(xp, w2p[3][pp], a1[3], false);        \
    }                                                                      \
    {                                                                      \
      h2 xt = __builtin_bit_cast(h2, (unsigned)(v[KS - 1] >> 32));         \
      a1[0] = __builtin_amdgcn_fdot2(xt, w2t[0], a1[0], false);            \
      a1[1] = __builtin_amdgcn_fdot2(xt, w2t[1], a1[1], false);            \
      a1[2] = __builtin_amdgcn_fdot2(xt, w2t[2], a1[2], false);            \
      a1[3] = __builtin_amdgcn_fdot2(xt, w2t[3], a1[3], false);            \
    }                                                                      \
    _Pragma("unroll") for (int m = 0; m < 4; ++m) {                        \
      float val = a0[m] + a1[m];                                           \
      bool in = (unsigned)(t - sm[m]) < (unsigned)olm[m];                  \
      float vm = in ? val : -3.0e38f;                                      \
      mx[m] = fmaxf(mx[m], vm);                                            \
      cnt[m] += (vm > 0.f) ? 1 : 0;                                        \
    }                                                                      \
    t += 8;                                                                \
  } while (0)

template <int KS>
__device__ __forceinline__ void rocket_body(
    const float* __restrict__ x, const float* __restrict__ w,
    const float* __restrict__ bias, const int* __restrict__ dil,
    const int* __restrict__ start, const int* __restrict__ out_len, int pm,
    const int* __restrict__ sortedj, const int2* __restrict__ quads,
    float* __restrict__ out, unsigned long long* xs, int tid, int bg, int qb) {
  constexpr int NP = (KS - 1) / 2;
  const int h = tid & 7;
  const int lb = (tid >> 3) & 3;
  const int qloc = tid >> 5;

  // quads span-descending with -1 tail: first empty => whole block empty
  if (quads[qb * QPB].x < 0) return;

  // stage x (4 batches) packed (c0,c1|c2,0) fp16 per position, zero sentinels
  for (int lbb = 0; lbb < NB; ++lbb) {
    const float* xb = x + (size_t)(bg * NB + lbb) * (CIN * SEQ);
    for (int pos = tid; pos < SEQ; pos += 256) {
      float f0 = xb[pos];
      float f1 = xb[SEQ + pos];
      float f2 = xb[2 * SEQ + pos];
      unsigned u0 = (unsigned)__builtin_bit_cast(unsigned short, (_Float16)f0);
      unsigned u1 = (unsigned)__builtin_bit_cast(unsigned short, (_Float16)f1);
      unsigned u2 = (unsigned)__builtin_bit_cast(unsigned short, (_Float16)f2);
      xs[lbb * 1002 + 1 + pos] =
          (unsigned long long)(u0 | (u1 << 16)) | ((unsigned long long)u2 << 32);
    }
  }
  if (tid < NB * 2) xs[(tid >> 1) * 1002 + (tid & 1) * 1001] = 0ULL;
  __syncthreads();

  int2 qr = quads[qb * QPB + qloc];
  if (qr.x < 0) return;

  int jm[4];
#pragma unroll
  for (int i = 0; i < 4; ++i) jm[i] = sortedj[min(qr.x + i, qr.y)];

  const int d = dil[jm[0]];  // class key guarantees same d (and same ks)

  int sm[4], olm[4];
  float bb[4];
  int tlo = 0x7fffffff, thi = 0;
#pragma unroll
  for (int m = 0; m < 4; ++m) {
    sm[m] = start[jm[m]];
    olm[m] = out_len[jm[m]];
    bb[m] = bias[jm[m]];
    tlo = min(tlo, sm[m]);
    thi = max(thi, sm[m] + olm[m]);
  }

  // weights: (c0,c1) per member per tap; c2 packed per TAP-PAIR (both fdot2
  // halves useful, f32 accumulation preserved); last (odd) tap keeps (c2,0).
  h2 wl[4][KS];
  h2 w2p[4][NP];
  h2 w2t[4];
#pragma unroll
  for (int m = 0; m < 4; ++m) {
    const float* wj = w + (size_t)jm[m] * (CIN * KM);
#pragma unroll
    for (int k = 0; k < KS; ++k) {
      h2 a;
      a.x = (_Float16)wj[k];
      a.y = (_Float16)wj[KM + k];
      wl[m][k] = a;
    }
#pragma unroll
    for (int pp = 0; pp < NP; ++pp) {
      h2 a;
      a.x = (_Float16)wj[2 * KM + 2 * pp];
      a.y = (_Float16)wj[2 * KM + 2 * pp + 1];
      w2p[m][pp] = a;
    }
    {
      h2 a;
      a.x = (_Float16)wj[2 * KM + (KS - 1)];
      a.y = (_Float16)0.0f;
      w2t[m] = a;
    }
  }

  const int lbase = lb * 1002;
  const int clo = lbase, chi = lbase + 1001;

  // interior (no clamp needed): p[0] >= clo  <=> t >= pm-1
  //                             p[KS-1] <= chi <=> t <= pm + SEQ - (KS-1)*d
  const int intLo = pm - 1;
  const int intHi = pm + SEQ - (KS - 1) * d;

  int t = tlo + h;  // interleaved: this thread handles t = tlo+h, +8, +16, ...
  int p[KS];
#pragma unroll
  for (int k = 0; k < KS; ++k) p[k] = lbase + 1 + (t - pm) + k * d;

  float mx[4] = {-3.0e38f, -3.0e38f, -3.0e38f, -3.0e38f};
  int cnt[4] = {0, 0, 0, 0};

  while (t < thi && t < intLo) ROCKET_STEP(true);   // head (low clamp)
  while (t < thi && t <= intHi) ROCKET_STEP(false); // interior (no clamp)
  while (t < thi) ROCKET_STEP(true);                // tail (high clamp)

  // reduce across the 8 tau-slices (lanes differing in bits 0..2)
#pragma unroll
  for (int m = 0; m < 4; ++m) {
#pragma unroll
    for (int off = 1; off < 8; off <<= 1) {
      mx[m] = fmaxf(mx[m], __shfl_xor(mx[m], off));
      cnt[m] += __shfl_xor(cnt[m], off);
    }
  }

  if (h == 0) {
    const int b = bg * NB + lb;
#pragma unroll
    for (int m = 0; m < 4; ++m) {
      float2 r;
      r.x = mx[m];
      r.y = (float)cnt[m] / (float)olm[m];
      *(float2*)(out + (size_t)b * (2 * N_K) + 2 * jm[m]) = r;
    }
  }
}

// waves_per_eu(2,3): pin the allocator's occupancy TARGET. Round-1 evidence:
// with only a min-waves bound the compiler chose 64 VGPRs (<68 resident
// weights!) -> per-iteration spill copies. Budget here is 512/3 ~= 170 VGPRs.
__global__ __attribute__((amdgpu_flat_work_group_size(256, 256),
                          amdgpu_waves_per_eu(2, 3)))
void rocket_kernel(const float* __restrict__ x, const float* __restrict__ w,
                   const float* __restrict__ bias, const int* __restrict__ dil,
                   const int* __restrict__ start,
                   const int* __restrict__ out_len,
                   const int* __restrict__ pad_max_p,
                   const int* __restrict__ sortedj,
                   const int2* __restrict__ quads, float* __restrict__ out) {
  __shared__ __align__(16) unsigned long long xs[NB * 1002];
  const int tid = threadIdx.x;
  const int bg = blockIdx.x & 3;
  const int qbg = blockIdx.x >> 2;
  const int region = qbg / QBPR;  // block-uniform: no wave divergence
  const int qb = qbg - region * QBPR;
  const int pm = pad_max_p[0];
  if (region == 0)
    rocket_body<7>(x, w, bias, dil, start, out_len, pm, sortedj, quads, out,
                   xs, tid, bg, qb);
  else if (region == 1)
    rocket_body<9>(x, w, bias, dil, start, out_len, pm, sortedj, quads + QREG,
                   out, xs, tid, bg, qb);
  else
    rocket_body<11>(x, w, bias, dil, start, out_len, pm, sortedj,
                    quads + 2 * QREG, out, xs, tid, bg, qb);
}

extern "C" void kernel_launch(void* const* d_in, const int* in_sizes, int n_in,
                              void* d_out, int out_size, void* d_ws,
                              size_t ws_size, hipStream_t stream) {
  const float* x       = (const float*)d_in[0];
  const float* weight  = (const float*)d_in[1];
  const float* bias    = (const float*)d_in[2];
  const int*   dil     = (const int*)d_in[3];
  const int*   start   = (const int*)d_in[4];
  const int*   out_len = (const int*)d_in[5];
  const int*   pad_max = (const int*)d_in[6];
  (void)in_sizes; (void)n_in; (void)out_size; (void)ws_size;

  int2* quads   = (int2*)d_ws;                                // 3*QREG int2
  int*  sortedj = (int*)((char*)d_ws + 3 * QREG * sizeof(int2));  // N_K ints

  prep_kernel<<<1, 1024, 0, stream>>>(dil, start, out_len, pad_max,
                                      sortedj, quads);

  rocket_kernel<<<3 * QBPR * 4, 256, 0, stream>>>(
      x, weight, bias, dil, start, out_len, pad_max, sortedj, quads,
      (float*)d_out);
}

// Round 3
// 314.233 us; speedup vs baseline: 1.0990x; 1.0028x over previous
//
#include <hip/hip_runtime.h>
#include <stdint.h>

#define N_K   10000
#define CIN   3
#define SEQ   1000
#define KM    11
#define NCLS  4096   // class key: ((d-1)*3 + ksidx)*4 + padflag*2 + padsize-bit
#define NSP   2048   // span (out_len) sort buckets per ks-region
#define QREG  2048   // groups per ks region (worst case ~1800)
#define QPB   8      // groups per block
#define QBPR  (QREG / QPB)   // 256 group-blocks per region
#define NB    4      // batches per block
#define LSTR  1012   // LDS segment stride in b64 units: 2024 dwords = 8 mod 32
                     // banks -> lb groups start at banks 0/8/16/24 (2/bank, free)

typedef _Float16 h2 __attribute__((ext_vector_type(2)));

// ---------------- prep: group j by (d, ks, pad-class), form TRIPLES,
// ---------------- partition by ks into 3 regions, span-sort within region ----
__global__ __launch_bounds__(1024) void prep_kernel(
    const int* __restrict__ dil, const int* __restrict__ start,
    const int* __restrict__ out_len, const int* __restrict__ pad_max_p,
    int* __restrict__ sortedj, int2* __restrict__ quads) {
  __shared__ int cA[NCLS];
  __shared__ int cB[NCLS];
  __shared__ int cC[3 * NSP];
  __shared__ int cD[3 * NSP];
  __shared__ int sh_total[3];
  const int tid = threadIdx.x;
  const int pm = pad_max_p[0];
  for (int i = tid; i < NCLS; i += 1024) cA[i] = 0;
  if (tid < 3) sh_total[tid] = 0;
  __syncthreads();
  // class histogram. ks recovered exactly: out_len = SEQ + 2*pads - d*(ks-1).
  for (int j = tid; j < N_K; j += 1024) {
    int d = dil[j];
    int pads = pm - start[j];
    int ks = (SEQ + 2 * pads - out_len[j]) / d + 1;
    int kk = ((d - 1) * 3 + ((ks - 7) >> 1)) * 4 + (pads > 0 ? 2 : 0) +
             (2 * pads > 7 * d ? 1 : 0);
    kk = min(kk, NCLS - 1);
    atomicAdd(&cA[kk], 1);
  }
  __syncthreads();
  {  // inclusive scan of cA; 12 rounds (even) -> result lands back in cA
    int* cur = cA; int* oth = cB;
    for (int off = 1; off < NCLS; off <<= 1) {
      for (int i = tid; i < NCLS; i += 1024) {
        int v = cur[i];
        if (i >= off) v += cur[i - off];
        oth[i] = v;
      }
      __syncthreads();
      int* tp = cur; cur = oth; oth = tp;
    }
  }
  for (int i = tid; i < NCLS; i += 1024) cB[i] = i ? cA[i - 1] : 0;  // exclusive
  __syncthreads();
  for (int j = tid; j < N_K; j += 1024) {
    int d = dil[j];
    int pads = pm - start[j];
    int ks = (SEQ + 2 * pads - out_len[j]) / d + 1;
    int kk = ((d - 1) * 3 + ((ks - 7) >> 1)) * 4 + (pads > 0 ? 2 : 0) +
             (2 * pads > 7 * d ? 1 : 0);
    kk = min(kk, NCLS - 1);
    int pos = atomicAdd(&cB[kk], 1);
    sortedj[pos] = j;
  }
  __syncthreads();
  for (int i = tid; i < 3 * NSP; i += 1024) cC[i] = 0;
  __syncthreads();
  // per class: count triples into (ks-region, span) bucket
  for (int c = tid; c < NCLS; c += 1024) {
    int incl = cA[c];
    int n = incl - (c ? cA[c - 1] : 0);
    if (n <= 0) continue;
    int st = incl - n;
    int nq = (n + 2) / 3;
    int ksidx = (c >> 2) % 3;
    int espan = out_len[sortedj[st]];
    int sb = ksidx * NSP + (NSP - 1) - min(espan, NSP - 1);  // descending span
    atomicAdd(&cC[sb], nq);
    atomicAdd(&sh_total[ksidx], nq);
  }
  __syncthreads();
  int* excl;
  {  // segmented (per-region) scan of cC; segments are NSP-aligned
    int* cur = cC; int* oth = cD;
    for (int off = 1; off < NSP; off <<= 1) {
      for (int i = tid; i < 3 * NSP; i += 1024) {
        int v = cur[i];
        if ((i & (NSP - 1)) >= off) v += cur[i - off];
        oth[i] = v;
      }
      __syncthreads();
      int* tp = cur; cur = oth; oth = tp;
    }
    for (int i = tid; i < 3 * NSP; i += 1024)
      oth[i] = (i & (NSP - 1)) ? cur[i - 1] : 0;  // per-segment exclusive
    __syncthreads();
    excl = oth;
  }
  // placement: triple = (first member offset in sortedj, last valid offset)
  for (int c = tid; c < NCLS; c += 1024) {
    int incl = cA[c];
    int n = incl - (c ? cA[c - 1] : 0);
    if (n <= 0) continue;
    int st = incl - n;
    int nq = (n + 2) / 3;
    int ksidx = (c >> 2) % 3;
    int espan = out_len[sortedj[st]];
    int sb = ksidx * NSP + (NSP - 1) - min(espan, NSP - 1);
    int pos = atomicAdd(&excl[sb], nq);
    for (int qq = 0; qq < nq; ++qq)
      quads[ksidx * QREG + pos + qq] = make_int2(st + 3 * qq, st + n - 1);
  }
  __syncthreads();
  for (int s = 0; s < 3; ++s)
    for (int i = sh_total[s] + tid; i < QREG; i += 1024)
      quads[s * QREG + i] = make_int2(-1, -1);
}

// ---------------- main kernel body, specialized on KS -----------------------
// block 256 = 8 triples x 4 batches x 8 tau-slices, t interleaved mod 8.
// G=3 members per group: weight live-set 33/42/51 regs (ks 7/9/11) so the
// whole loop state fits the ~102-VGPR budget (512/5 waves) -> no AGPR churn.
// Running-pointer tap addressing (1 live addr reg) + paired tap consumption
// (v dead right after use) keep the rest of the live set small.
#define ROCKET_STEP(CLAMPED)                                                  \
  do {                                                                        \
    float a0[3] = {bb[0], bb[1], bb[2]};                                      \
    float a1[3] = {0.f, 0.f, 0.f};                                            \
    int qq = pb;                                                              \
    _Pragma("unroll") for (int pp = 0; pp < NP; ++pp) {                       \
      int qA = qq; qq += d;                                                   \
      int qB = qq; qq += d;                                                   \
      if (CLAMPED) {                                                          \
        qA = min(max(qA, clo), chi);                                          \
        qB = min(max(qB, clo), chi);                                          \
      }                                                                       \
      unsigned long long vA = xs[qA];                                         \
      unsigned long long vB = xs[qB];                                         \
      h2 xA = __builtin_bit_cast(h2, (unsigned)vA);                           \
      h2 xB = __builtin_bit_cast(h2, (unsigned)vB);                           \
      a0[0] = __builtin_amdgcn_fdot2(xA, wl[0][2 * pp], a0[0], false);        \
      a0[1] = __builtin_amdgcn_fdot2(xA, wl[1][2 * pp], a0[1], false);        \
      a0[2] = __builtin_amdgcn_fdot2(xA, wl[2][2 * pp], a0[2], false);        \
      a0[0] = __builtin_amdgcn_fdot2(xB, wl[0][2 * pp + 1], a0[0], false);    \
      a0[1] = __builtin_amdgcn_fdot2(xB, wl[1][2 * pp + 1], a0[1], false);    \
      a0[2] = __builtin_amdgcn_fdot2(xB, wl[2][2 * pp + 1], a0[2], false);    \
      unsigned hA = (unsigned)(vA >> 32);                                     \
      unsigned hB = (unsigned)(vB >> 32);                                     \
      h2 xp = __builtin_bit_cast(                                             \
          h2, __builtin_amdgcn_perm(hB, hA, 0x05040100u));                    \
      a1[0] = __builtin_amdgcn_fdot2(xp, w2p[0][pp], a1[0], false);           \
      a1[1] = __builtin_amdgcn_fdot2(xp, w2p[1][pp], a1[1], false);           \
      a1[2] = __builtin_amdgcn_fdot2(xp, w2p[2][pp], a1[2], false);           \
    }                                                                         \
    {                                                                         \
      int qT = qq;                                                            \
      if (CLAMPED) qT = min(max(qT, clo), chi);                               \
      unsigned long long vT = xs[qT];                                         \
      h2 xT = __builtin_bit_cast(h2, (unsigned)vT);                           \
      a0[0] = __builtin_amdgcn_fdot2(xT, wl[0][KS - 1], a0[0], false);        \
      a0[1] = __builtin_amdgcn_fdot2(xT, wl[1][KS - 1], a0[1], false);        \
      a0[2] = __builtin_amdgcn_fdot2(xT, wl[2][KS - 1], a0[2], false);        \
      h2 xt = __builtin_bit_cast(h2, (unsigned)(vT >> 32));                   \
      a1[0] = __builtin_amdgcn_fdot2(xt, w2t[0], a1[0], false);               \
      a1[1] = __builtin_amdgcn_fdot2(xt, w2t[1], a1[1], false);               \
      a1[2] = __builtin_amdgcn_fdot2(xt, w2t[2], a1[2], false);               \
    }                                                                         \
    _Pragma("unroll") for (int m = 0; m < 3; ++m) {                           \
      float val = a0[m] + a1[m];                                              \
      bool in = (unsigned)(t - sm[m]) < (unsigned)olm[m];                     \
      float vm = in ? val : -3.0e38f;                                         \
      mx[m] = fmaxf(mx[m], vm);                                               \
      cnt[m] += (vm > 0.f) ? 1 : 0;                                           \
    }                                                                         \
    pb += 8;                                                                  \
    t += 8;                                                                   \
  } while (0)

template <int KS>
__device__ __forceinline__ void rocket_body(
    const float* __restrict__ x, const float* __restrict__ w,
    const float* __restrict__ bias, const int* __restrict__ dil,
    const int* __restrict__ start, const int* __restrict__ out_len, int pm,
    const int* __restrict__ sortedj, const int2* __restrict__ quads,
    float* __restrict__ out, unsigned long long* xs, int tid, int bg, int qb) {
  constexpr int NP = (KS - 1) / 2;
  const int h = tid & 7;
  const int lb = (tid >> 3) & 3;
  const int qloc = tid >> 5;

  // groups span-descending with -1 tail: first empty => whole block empty
  if (quads[qb * QPB].x < 0) return;

  // stage x (4 batches) packed (c0,c1|c2,0) fp16 per position, zero sentinels
  for (int lbb = 0; lbb < NB; ++lbb) {
    const float* xb = x + (size_t)(bg * NB + lbb) * (CIN * SEQ);
    for (int pos = tid; pos < SEQ; pos += 256) {
      float f0 = xb[pos];
      float f1 = xb[SEQ + pos];
      float f2 = xb[2 * SEQ + pos];
      unsigned u0 = (unsigned)__builtin_bit_cast(unsigned short, (_Float16)f0);
      unsigned u1 = (unsigned)__builtin_bit_cast(unsigned short, (_Float16)f1);
      unsigned u2 = (unsigned)__builtin_bit_cast(unsigned short, (_Float16)f2);
      xs[lbb * LSTR + 1 + pos] =
          (unsigned long long)(u0 | (u1 << 16)) | ((unsigned long long)u2 << 32);
    }
  }
  if (tid < NB * 2) xs[(tid >> 1) * LSTR + (tid & 1) * 1001] = 0ULL;
  __syncthreads();

  int2 qr = quads[qb * QPB + qloc];
  if (qr.x < 0) return;

  int jm[3];
#pragma unroll
  for (int i = 0; i < 3; ++i) jm[i] = sortedj[min(qr.x + i, qr.y)];

  const int d = dil[jm[0]];  // class key guarantees same d (and same ks)

  int sm[3], olm[3];
  float bb[3];
  int tlo = 0x7fffffff, thi = 0;
#pragma unroll
  for (int m = 0; m < 3; ++m) {
    sm[m] = start[jm[m]];
    olm[m] = out_len[jm[m]];
    bb[m] = bias[jm[m]];
    tlo = min(tlo, sm[m]);
    thi = max(thi, sm[m] + olm[m]);
  }

  // weights: (c0,c1) per member per tap; c2 packed per TAP-PAIR (both fdot2
  // halves useful, f32 accumulation preserved); last (odd) tap keeps (c2,0).
  h2 wl[3][KS];
  h2 w2p[3][NP];
  h2 w2t[3];
#pragma unroll
  for (int m = 0; m < 3; ++m) {
    const float* wj = w + (size_t)jm[m] * (CIN * KM);
#pragma unroll
    for (int k = 0; k < KS; ++k) {
      h2 a;
      a.x = (_Float16)wj[k];
      a.y = (_Float16)wj[KM + k];
      wl[m][k] = a;
    }
#pragma unroll
    for (int pp = 0; pp < NP; ++pp) {
      h2 a;
      a.x = (_Float16)wj[2 * KM + 2 * pp];
      a.y = (_Float16)wj[2 * KM + 2 * pp + 1];
      w2p[m][pp] = a;
    }
    {
      h2 a;
      a.x = (_Float16)wj[2 * KM + (KS - 1)];
      a.y = (_Float16)0.0f;
      w2t[m] = a;
    }
  }

  const int lbase = lb * LSTR;
  const int clo = lbase, chi = lbase + 1001;

  // interior (no clamp needed): pb >= clo          <=> t >= pm-1
  //                             pb+(KS-1)d <= chi  <=> t <= pm + SEQ - (KS-1)*d
  const int intLo = pm - 1;
  const int intHi = pm + SEQ - (KS - 1) * d;

  int t = tlo + h;  // interleaved: this thread handles t = tlo+h, +8, +16, ...
  int pb = lbase + 1 + (t - pm);  // tap-0 index; taps advance by running +d

  float mx[3] = {-3.0e38f, -3.0e38f, -3.0e38f};
  int cnt[3] = {0, 0, 0};

  while (t < thi && t < intLo) ROCKET_STEP(true);   // head (low clamp)
  while (t < thi && t <= intHi) ROCKET_STEP(false); // interior (no clamp)
  while (t < thi) ROCKET_STEP(true);                // tail (high clamp)

  // reduce across the 8 tau-slices (lanes differing in bits 0..2)
#pragma unroll
  for (int m = 0; m < 3; ++m) {
#pragma unroll
    for (int off = 1; off < 8; off <<= 1) {
      mx[m] = fmaxf(mx[m], __shfl_xor(mx[m], off));
      cnt[m] += __shfl_xor(cnt[m], off);
    }
  }

  if (h == 0) {
    const int b = bg * NB + lb;
#pragma unroll
    for (int m = 0; m < 3; ++m) {
      float2 r;
      r.x = mx[m];
      r.y = (float)cnt[m] / (float)olm[m];
      *(float2*)(out + (size_t)b * (2 * N_K) + 2 * jm[m]) = r;
    }
  }
}

// waves_per_eu(5): LDS (4*LSTR*8 = 32384 B) caps residency at 5 blocks/CU =
// exactly 5 waves/EU, so min=5 is achievable; it sets the VGPR budget to
// 512/5 ~= 102 without capping occupancy below what LDS already allows.
__global__ __attribute__((amdgpu_flat_work_group_size(256, 256),
                          amdgpu_waves_per_eu(5)))
void rocket_kernel(const float* __restrict__ x, const float* __restrict__ w,
                   const float* __restrict__ bias, const int* __restrict__ dil,
                   const int* __restrict__ start,
                   const int* __restrict__ out_len,
                   const int* __restrict__ pad_max_p,
                   const int* __restrict__ sortedj,
                   const int2* __restrict__ quads, float* __restrict__ out) {
  __shared__ __align__(16) unsigned long long xs[NB * LSTR];
  const int tid = threadIdx.x;
  const int bg = blockIdx.x & 3;
  const int qbg = blockIdx.x >> 2;
  const int region = qbg / QBPR;  // block-uniform: no wave divergence
  const int qb = qbg - region * QBPR;
  const int pm = pad_max_p[0];
  if (region == 0)
    rocket_body<7>(x, w, bias, dil, start, out_len, pm, sortedj, quads, out,
                   xs, tid, bg, qb);
  else if (region == 1)
    rocket_body<9>(x, w, bias, dil, start, out_len, pm, sortedj, quads + QREG,
                   out, xs, tid, bg, qb);
  else
    rocket_body<11>(x, w, bias, dil, start, out_len, pm, sortedj,
                    quads + 2 * QREG, out, xs, tid, bg, qb);
}

extern "C" void kernel_launch(void* const* d_in, const int* in_sizes, int n_in,
                              void* d_out, int out_size, void* d_ws,
                              size_t ws_size, hipStream_t stream) {
  const float* x       = (const float*)d_in[0];
  const float* weight  = (const float*)d_in[1];
  const float* bias    = (const float*)d_in[2];
  const int*   dil     = (const int*)d_in[3];
  const int*   start   = (const int*)d_in[4];
  const int*   out_len = (const int*)d_in[5];
  const int*   pad_max = (const int*)d_in[6];
  (void)in_sizes; (void)n_in; (void)out_size; (void)ws_size;

  int2* quads   = (int2*)d_ws;                                // 3*QREG int2
  int*  sortedj = (int*)((char*)d_ws + 3 * QREG * sizeof(int2));  // N_K ints

  prep_kernel<<<1, 1024, 0, stream>>>(dil, start, out_len, pad_max,
                                      sortedj, quads);

  rocket_kernel<<<3 * QBPR * 4, 256, 0, stream>>>(
      x, weight, bias, dil, start, out_len, pad_max, sortedj, quads,
      (float*)d_out);
}

// Round 4
// 265.712 us; speedup vs baseline: 1.2997x; 1.1826x over previous
//
#include <hip/hip_runtime.h>
#include <stdint.h>

#define N_K   10000
#define CIN   3
#define SEQ   1000
#define KM    11
#define NCLS  4096   // class key: ((d-1)*3 + ksidx)*4 + padflag*2 + padsize-bit
#define NSP   2048   // span (out_len) sort buckets per ks-region
#define QREG  2048   // groups per ks region (worst case ~1500)
#define QPB   4      // groups (triples) per block = 1 per wave
#define QBPR  (QREG / QPB)   // 512 group-blocks per region
#define NB    4      // batches per block
#define LSTR  1012   // LDS segment stride in b64 units: 2024 dwords = 8 mod 32
                     // banks -> lb segments start at banks 0/8/16/24

typedef _Float16 h2 __attribute__((ext_vector_type(2)));

// ---------------- prep: group j by (d, ks, pad-class), form TRIPLES,
// ---------------- partition by ks into 3 regions, span-sort within region ----
__global__ __launch_bounds__(1024) void prep_kernel(
    const int* __restrict__ dil, const int* __restrict__ start,
    const int* __restrict__ out_len, const int* __restrict__ pad_max_p,
    int* __restrict__ sortedj, int2* __restrict__ quads) {
  __shared__ int cA[NCLS];
  __shared__ int cB[NCLS];
  __shared__ int cC[3 * NSP];
  __shared__ int cD[3 * NSP];
  __shared__ int sh_total[3];
  const int tid = threadIdx.x;
  const int pm = pad_max_p[0];
  for (int i = tid; i < NCLS; i += 1024) cA[i] = 0;
  if (tid < 3) sh_total[tid] = 0;
  __syncthreads();
  // class histogram. ks recovered exactly: out_len = SEQ + 2*pads - d*(ks-1).
  for (int j = tid; j < N_K; j += 1024) {
    int d = dil[j];
    int pads = pm - start[j];
    int ks = (SEQ + 2 * pads - out_len[j]) / d + 1;
    int kk = ((d - 1) * 3 + ((ks - 7) >> 1)) * 4 + (pads > 0 ? 2 : 0) +
             (2 * pads > 7 * d ? 1 : 0);
    kk = min(kk, NCLS - 1);
    atomicAdd(&cA[kk], 1);
  }
  __syncthreads();
  {  // inclusive scan of cA; 12 rounds (even) -> result lands back in cA
    int* cur = cA; int* oth = cB;
    for (int off = 1; off < NCLS; off <<= 1) {
      for (int i = tid; i < NCLS; i += 1024) {
        int v = cur[i];
        if (i >= off) v += cur[i - off];
        oth[i] = v;
      }
      __syncthreads();
      int* tp = cur; cur = oth; oth = tp;
    }
  }
  for (int i = tid; i < NCLS; i += 1024) cB[i] = i ? cA[i - 1] : 0;  // exclusive
  __syncthreads();
  for (int j = tid; j < N_K; j += 1024) {
    int d = dil[j];
    int pads = pm - start[j];
    int ks = (SEQ + 2 * pads - out_len[j]) / d + 1;
    int kk = ((d - 1) * 3 + ((ks - 7) >> 1)) * 4 + (pads > 0 ? 2 : 0) +
             (2 * pads > 7 * d ? 1 : 0);
    kk = min(kk, NCLS - 1);
    int pos = atomicAdd(&cB[kk], 1);
    sortedj[pos] = j;
  }
  __syncthreads();
  for (int i = tid; i < 3 * NSP; i += 1024) cC[i] = 0;
  __syncthreads();
  // per class: count triples into (ks-region, span) bucket
  for (int c = tid; c < NCLS; c += 1024) {
    int incl = cA[c];
    int n = incl - (c ? cA[c - 1] : 0);
    if (n <= 0) continue;
    int st = incl - n;
    int nq = (n + 2) / 3;
    int ksidx = (c >> 2) % 3;
    int espan = out_len[sortedj[st]];
    int sb = ksidx * NSP + (NSP - 1) - min(espan, NSP - 1);  // descending span
    atomicAdd(&cC[sb], nq);
    atomicAdd(&sh_total[ksidx], nq);
  }
  __syncthreads();
  int* excl;
  {  // segmented (per-region) scan of cC; segments are NSP-aligned
    int* cur = cC; int* oth = cD;
    for (int off = 1; off < NSP; off <<= 1) {
      for (int i = tid; i < 3 * NSP; i += 1024) {
        int v = cur[i];
        if ((i & (NSP - 1)) >= off) v += cur[i - off];
        oth[i] = v;
      }
      __syncthreads();
      int* tp = cur; cur = oth; oth = tp;
    }
    for (int i = tid; i < 3 * NSP; i += 1024)
      oth[i] = (i & (NSP - 1)) ? cur[i - 1] : 0;  // per-segment exclusive
    __syncthreads();
    excl = oth;
  }
  // placement: triple = (first member offset in sortedj, last valid offset)
  for (int c = tid; c < NCLS; c += 1024) {
    int incl = cA[c];
    int n = incl - (c ? cA[c - 1] : 0);
    if (n <= 0) continue;
    int st = incl - n;
    int nq = (n + 2) / 3;
    int ksidx = (c >> 2) % 3;
    int espan = out_len[sortedj[st]];
    int sb = ksidx * NSP + (NSP - 1) - min(espan, NSP - 1);
    int pos = atomicAdd(&excl[sb], nq);
    for (int qq = 0; qq < nq; ++qq)
      quads[ksidx * QREG + pos + qq] = make_int2(st + 3 * qq, st + n - 1);
  }
  __syncthreads();
  for (int s = 0; s < 3; ++s)
    for (int i = sh_total[s] + tid; i < QREG; i += 1024)
      quads[s * QREG + i] = make_int2(-1, -1);
}

// ---------------- main kernel body, specialized on KS -----------------------
// block 256 = 4 waves; each WAVE owns ONE triple (16 tau-slices x 4 batches).
// All triple state (jm, d, sm, olm, bias, packed f16 weights, k*d offsets) is
// wave-uniform -> readfirstlane -> SGPRs. v_dot2_f32_f16 reads the weight as
// its 1 allowed SGPR operand, so the vector live set is ~35 regs: nothing for
// the allocator to spill (rounds 0-3: weights in VGPRs -> AGPR churn/scratch).
#define W(u) __builtin_bit_cast(h2, u)
#define ROCKET_STEP(CLAMPED)                                                  \
  do {                                                                        \
    float a0[3] = {bb[0], bb[1], bb[2]};                                      \
    float a1[3] = {0.f, 0.f, 0.f};                                            \
    _Pragma("unroll") for (int pp = 0; pp < NP; ++pp) {                       \
      int qA = pb + kds[2 * pp];                                              \
      int qB = pb + kds[2 * pp + 1];                                          \
      if (CLAMPED) {                                                          \
        qA = min(max(qA, clo), chi);                                          \
        qB = min(max(qB, clo), chi);                                          \
      }                                                                       \
      unsigned long long vA = xs[qA];                                         \
      unsigned long long vB = xs[qB];                                         \
      h2 xA = __builtin_bit_cast(h2, (unsigned)vA);                           \
      h2 xB = __builtin_bit_cast(h2, (unsigned)vB);                           \
      a0[0] = __builtin_amdgcn_fdot2(xA, W(wsl[0][2 * pp]), a0[0], false);    \
      a0[1] = __builtin_amdgcn_fdot2(xA, W(wsl[1][2 * pp]), a0[1], false);    \
      a0[2] = __builtin_amdgcn_fdot2(xA, W(wsl[2][2 * pp]), a0[2], false);    \
      a0[0] = __builtin_amdgcn_fdot2(xB, W(wsl[0][2 * pp + 1]), a0[0], false);\
      a0[1] = __builtin_amdgcn_fdot2(xB, W(wsl[1][2 * pp + 1]), a0[1], false);\
      a0[2] = __builtin_amdgcn_fdot2(xB, W(wsl[2][2 * pp + 1]), a0[2], false);\
      unsigned hA = (unsigned)(vA >> 32);                                     \
      unsigned hB = (unsigned)(vB >> 32);                                     \
      h2 xp = __builtin_bit_cast(                                             \
          h2, __builtin_amdgcn_perm(hB, hA, 0x05040100u));                    \
      a1[0] = __builtin_amdgcn_fdot2(xp, W(wsp[0][pp]), a1[0], false);        \
      a1[1] = __builtin_amdgcn_fdot2(xp, W(wsp[1][pp]), a1[1], false);        \
      a1[2] = __builtin_amdgcn_fdot2(xp, W(wsp[2][pp]), a1[2], false);        \
    }                                                                         \
    {                                                                         \
      int qT = pb + kds[KS - 1];                                              \
      if (CLAMPED) qT = min(max(qT, clo), chi);                               \
      unsigned long long vT = xs[qT];                                         \
      h2 xT = __builtin_bit_cast(h2, (unsigned)vT);                           \
      a0[0] = __builtin_amdgcn_fdot2(xT, W(wsl[0][KS - 1]), a0[0], false);    \
      a0[1] = __builtin_amdgcn_fdot2(xT, W(wsl[1][KS - 1]), a0[1], false);    \
      a0[2] = __builtin_amdgcn_fdot2(xT, W(wsl[2][KS - 1]), a0[2], false);    \
      h2 xt = __builtin_bit_cast(h2, (unsigned)(vT >> 32));                   \
      a1[0] = __builtin_amdgcn_fdot2(xt, W(wst[0]), a1[0], false);            \
      a1[1] = __builtin_amdgcn_fdot2(xt, W(wst[1]), a1[1], false);            \
      a1[2] = __builtin_amdgcn_fdot2(xt, W(wst[2]), a1[2], false);            \
    }                                                                         \
    _Pragma("unroll") for (int m = 0; m < 3; ++m) {                           \
      float val = a0[m] + a1[m];                                              \
      bool in = (unsigned)(t - sm[m]) < (unsigned)olm[m];                     \
      float vm = in ? val : -3.0e38f;                                         \
      mx[m] = fmaxf(mx[m], vm);                                               \
      cnt[m] += (vm > 0.f) ? 1 : 0;                                           \
    }                                                                         \
    pb += 16;                                                                 \
    t += 16;                                                                  \
  } while (0)

template <int KS>
__device__ __forceinline__ void rocket_body(
    const float* __restrict__ x, const float* __restrict__ w,
    const float* __restrict__ bias, const int* __restrict__ dil,
    const int* __restrict__ start, const int* __restrict__ out_len, int pm,
    const int* __restrict__ sortedj, const int2* __restrict__ quads,
    float* __restrict__ out, unsigned long long* xs, int tid, int bg, int qb) {
  constexpr int NP = (KS - 1) / 2;
  const int h = tid & 15;          // 16 tau-slices
  const int lb = (tid >> 4) & 3;   // 4 batches
  const int qloc = tid >> 6;       // wave id = triple id

  // groups span-descending with -1 tail: first empty => whole block empty
  if (quads[qb * QPB].x < 0) return;

  // stage x (4 batches) packed (c0,c1|c2,0) fp16 per position, zero sentinels
  for (int lbb = 0; lbb < NB; ++lbb) {
    const float* xb = x + (size_t)(bg * NB + lbb) * (CIN * SEQ);
    for (int pos = tid; pos < SEQ; pos += 256) {
      float f0 = xb[pos];
      float f1 = xb[SEQ + pos];
      float f2 = xb[2 * SEQ + pos];
      unsigned u0 = (unsigned)__builtin_bit_cast(unsigned short, (_Float16)f0);
      unsigned u1 = (unsigned)__builtin_bit_cast(unsigned short, (_Float16)f1);
      unsigned u2 = (unsigned)__builtin_bit_cast(unsigned short, (_Float16)f2);
      xs[lbb * LSTR + 1 + pos] =
          (unsigned long long)(u0 | (u1 << 16)) | ((unsigned long long)u2 << 32);
    }
  }
  if (tid < NB * 2) xs[(tid >> 1) * LSTR + (tid & 1) * 1001] = 0ULL;
  __syncthreads();

  int2 qr = quads[qb * QPB + qloc];
  if (qr.x < 0) return;

  // ---- wave-uniform triple state -> SGPRs ----------------------------------
  int jm[3];
#pragma unroll
  for (int i = 0; i < 3; ++i)
    jm[i] = __builtin_amdgcn_readfirstlane(sortedj[min(qr.x + i, qr.y)]);

  const int d = __builtin_amdgcn_readfirstlane(dil[jm[0]]);

  int sm[3], olm[3];
  float bb[3];
  int tlo = 0x7fffffff, thi = 0;
#pragma unroll
  for (int m = 0; m < 3; ++m) {
    sm[m] = __builtin_amdgcn_readfirstlane(start[jm[m]]);
    olm[m] = __builtin_amdgcn_readfirstlane(out_len[jm[m]]);
    bb[m] = __builtin_bit_cast(
        float, __builtin_amdgcn_readfirstlane(
                   __builtin_bit_cast(unsigned, bias[jm[m]])));
    tlo = min(tlo, sm[m]);
    thi = max(thi, sm[m] + olm[m]);
  }

  // packed f16 weights, readfirstlane'd into SGPRs:
  // wsl[m][k] = (w_c0[k], w_c1[k]); wsp[m][pp] = (w_c2[2pp], w_c2[2pp+1]);
  // wst[m] = (w_c2[KS-1], 0)
  unsigned wsl[3][KS], wsp[3][NP], wst[3];
#pragma unroll
  for (int m = 0; m < 3; ++m) {
    const float* wj = w + (size_t)jm[m] * (CIN * KM);
#pragma unroll
    for (int k = 0; k < KS; ++k) {
      h2 a;
      a.x = (_Float16)wj[k];
      a.y = (_Float16)wj[KM + k];
      wsl[m][k] =
          __builtin_amdgcn_readfirstlane(__builtin_bit_cast(unsigned, a));
    }
#pragma unroll
    for (int pp = 0; pp < NP; ++pp) {
      h2 a;
      a.x = (_Float16)wj[2 * KM + 2 * pp];
      a.y = (_Float16)wj[2 * KM + 2 * pp + 1];
      wsp[m][pp] =
          __builtin_amdgcn_readfirstlane(__builtin_bit_cast(unsigned, a));
    }
    {
      h2 a;
      a.x = (_Float16)wj[2 * KM + (KS - 1)];
      a.y = (_Float16)0.0f;
      wst[m] =
          __builtin_amdgcn_readfirstlane(__builtin_bit_cast(unsigned, a));
    }
  }

  // tap offsets k*d: wave-uniform -> SGPRs; per-step addresses are KS
  // INDEPENDENT v_adds from pb (no serial chain)
  int kds[KS];
#pragma unroll
  for (int k = 0; k < KS; ++k) kds[k] = __builtin_amdgcn_readfirstlane(k * d);

  const int lbase = lb * LSTR;
  const int clo = lbase, chi = lbase + 1001;

  // interior (no clamp needed): pb >= clo          <=> t >= pm-1
  //                             pb+(KS-1)d <= chi  <=> t <= pm + SEQ - (KS-1)*d
  const int intLo = pm - 1;
  const int intHi = pm + SEQ - (KS - 1) * d;

  int t = tlo + h;  // interleaved: this lane handles t = tlo+h, +16, +32, ...
  int pb = lbase + 1 + (t - pm);  // tap-0 LDS index (b64 units)

  float mx[3] = {-3.0e38f, -3.0e38f, -3.0e38f};
  int cnt[3] = {0, 0, 0};

  while (t < thi && t < intLo) ROCKET_STEP(true);   // head (low clamp)
  while (t < thi && t <= intHi) ROCKET_STEP(false); // interior (no clamp)
  while (t < thi) ROCKET_STEP(true);                // tail (high clamp)

  // reduce across the 16 tau-slices (lanes differing in bits 0..3)
#pragma unroll
  for (int m = 0; m < 3; ++m) {
#pragma unroll
    for (int off = 1; off < 16; off <<= 1) {
      mx[m] = fmaxf(mx[m], __shfl_xor(mx[m], off));
      cnt[m] += __shfl_xor(cnt[m], off);
    }
  }

  if (h == 0) {
    const int b = bg * NB + lb;
#pragma unroll
    for (int m = 0; m < 3; ++m) {
      float2 r;
      r.x = mx[m];
      r.y = (float)cnt[m] / (float)olm[m];
      *(float2*)(out + (size_t)b * (2 * N_K) + 2 * jm[m]) = r;
    }
  }
}

// No occupancy attribute: LDS (32384 B) caps residency at 5 blocks/CU anyway,
// and the vector live set is now ~35 regs -- nothing to constrain.
__global__ __launch_bounds__(256) void rocket_kernel(
    const float* __restrict__ x, const float* __restrict__ w,
    const float* __restrict__ bias, const int* __restrict__ dil,
    const int* __restrict__ start, const int* __restrict__ out_len,
    const int* __restrict__ pad_max_p, const int* __restrict__ sortedj,
    const int2* __restrict__ quads, float* __restrict__ out) {
  __shared__ __align__(16) unsigned long long xs[NB * LSTR];
  const int tid = threadIdx.x;
  const int bg = blockIdx.x & 3;
  const int qbg = blockIdx.x >> 2;
  const int region = qbg / QBPR;  // block-uniform: no wave divergence
  const int qb = qbg - region * QBPR;
  const int pm = pad_max_p[0];
  if (region == 0)
    rocket_body<7>(x, w, bias, dil, start, out_len, pm, sortedj, quads, out,
                   xs, tid, bg, qb);
  else if (region == 1)
    rocket_body<9>(x, w, bias, dil, start, out_len, pm, sortedj, quads + QREG,
                   out, xs, tid, bg, qb);
  else
    rocket_body<11>(x, w, bias, dil, start, out_len, pm, sortedj,
                    quads + 2 * QREG, out, xs, tid, bg, qb);
}

extern "C" void kernel_launch(void* const* d_in, const int* in_sizes, int n_in,
                              void* d_out, int out_size, void* d_ws,
                              size_t ws_size, hipStream_t stream) {
  const float* x       = (const float*)d_in[0];
  const float* weight  = (const float*)d_in[1];
  const float* bias    = (const float*)d_in[2];
  const int*   dil     = (const int*)d_in[3];
  const int*   start   = (const int*)d_in[4];
  const int*   out_len = (const int*)d_in[5];
  const int*   pad_max = (const int*)d_in[6];
  (void)in_sizes; (void)n_in; (void)out_size; (void)ws_size;

  int2* quads   = (int2*)d_ws;                                // 3*QREG int2
  int*  sortedj = (int*)((char*)d_ws + 3 * QREG * sizeof(int2));  // N_K ints

  prep_kernel<<<1, 1024, 0, stream>>>(dil, start, out_len, pad_max,
                                      sortedj, quads);

  rocket_kernel<<<3 * QBPR * 4, 256, 0, stream>>>(
      x, weight, bias, dil, start, out_len, pad_max, sortedj, quads,
      (float*)d_out);
}